// Round 20
// baseline (2795.366 us; speedup 1.0000x reference)
//
#include <hip/hip_runtime.h>
#include <hip/hip_bf16.h>
#include <hip/hip_fp8.h>
#include <math.h>

#define IGNORE_INDEX (-100)

static constexpr int Dc = 1024, Vc = 128000;
static constexpr int Mrows = 2048;        // B*S
static constexpr int Kdim = 1024;
static constexpr int NT64 = Kdim / 64;    // 16 k-tiles of 64 fp8 elems
static constexpr int NCHUNK = Vc / 64;    // 2000 partial chunks per row

typedef int i32x4 __attribute__((ext_vector_type(4)));
typedef int i32x8 __attribute__((ext_vector_type(8)));
typedef float f32x16 __attribute__((ext_vector_type(16)));

// ---- cast fp32 -> fp8 e4m3, FRAGMENT-MAJOR pack for 32x32x64 MX MFMA -------
// Frag tile = 32 rows x 64 k = 2048 B, stored as [khalf-chunk][lane][sub]:
//   lane = (row&31) + 32*((k>>5)&1)   (standard 32x32 row<->lane mapping)
//   byte pos = ((k>>4)&1)*1024 + lane*16 + (k&15)
// k-permutation note: ANY k-bijection is correct as long as A and B packs use
// the SAME one (dot products are k-permutation-invariant and unit scales make
// 32-block boundaries irrelevant). The lane*16 split makes the GEMM's
// ds_read_b128 2-way bank aliasing (free, m136). Buffer = [rt][kt] frag tiles.
__global__ void cast_f32_fp8_pack(const float* __restrict__ in, uchar* __restrict__ out,
                                  size_t n8) {
  size_t i = (size_t)blockIdx.x * blockDim.x + threadIdx.x;
  size_t stride = (size_t)gridDim.x * blockDim.x;
  for (; i < n8; i += stride) {
    size_t q = i * 8;                      // output byte
    size_t ftile = q >> 11;                // rt*NT64 + kt
    int rem = (int)(q & 2047);
    int chunk = rem >> 10;                 // (k>>4)&1
    int lane = (rem >> 4) & 63;
    int sub0 = rem & 15;                   // 0 or 8
    size_t rt = ftile >> 4;                // / NT64
    int kt = (int)(ftile & 15);
    size_t row = rt * 32 + (lane & 31);
    int k = kt * 64 + (lane >> 5) * 32 + chunk * 16 + sub0;
    const float* p = in + row * Kdim + k;
    float4 v0 = *reinterpret_cast<const float4*>(p);
    float4 v1 = *reinterpret_cast<const float4*>(p + 4);
    union { uchar b[8]; unsigned long long u; } o;
    o.b[0] = __hip_fp8_e4m3(v0.x).__x; o.b[1] = __hip_fp8_e4m3(v0.y).__x;
    o.b[2] = __hip_fp8_e4m3(v0.z).__x; o.b[3] = __hip_fp8_e4m3(v0.w).__x;
    o.b[4] = __hip_fp8_e4m3(v1.x).__x; o.b[5] = __hip_fp8_e4m3(v1.y).__x;
    o.b[6] = __hip_fp8_e4m3(v1.z).__x; o.b[7] = __hip_fp8_e4m3(v1.w).__x;
    reinterpret_cast<unsigned long long*>(out)[i] = o.u;
  }
}

// ---------------- target logits: fp32 dot(hidden[r], weight[t[r]]) — exact ----
__global__ void tgt_kernel(const float* __restrict__ hidden, const float* __restrict__ weight,
                           const int* __restrict__ targets, float* __restrict__ tgt) {
  int row = blockIdx.x * 4 + (threadIdx.x >> 6);
  int lane = threadIdx.x & 63;
  if (row >= Mrows) return;
  int t = targets[row];
  float sum = 0.f;
  if (t != IGNORE_INDEX) {
    const float* h = hidden + (size_t)row * Kdim;
    const float* wv = weight + (size_t)t * Kdim;
    for (int k = lane * 4; k < Kdim; k += 64 * 4) {
      float4 a = *reinterpret_cast<const float4*>(h + k);
      float4 b = *reinterpret_cast<const float4*>(wv + k);
      sum += a.x * b.x + a.y * b.y + a.z * b.z + a.w * b.w;
    }
  }
  #pragma unroll
  for (int d = 1; d < 64; d <<= 1) sum += __shfl_xor(sum, d);
  if (lane == 0) tgt[row] = sum;
}

// -- 128x256 8-wave 2-BLOCK/CU ring-3 MX-FP8 GEMM + fused partial LSE --------
// MFMA: mfma_scale_f32_32x32x64_f8f6f4 with unit scales (e8m0 0x7F = 2^0):
// 2x the non-scaled fp8 rate (4686 TF m59) -> MFMA floor 114us. R11-R19
// measured every schedule/data-path variant pinned at 40-45% MfmaUtil
// (~1020 TF) at the non-scaled rate; halving MFMA pipe time is the remaining
// catalog lever. Wave = 64x64 out = 2x2 frags of 32x32; acc = 4x16 f32.
// LDS: ring-3 x 24KB (A 4 frags + B 8 frags, packed fragment-major; reads =
// ds_read_b128 at lane*16 -> 2-way free, NO swizzle). Stage = 3 linear 16B
// glds/thread/tile; counted vmcnt(3) (R13-proven wave-uniform pattern).
#define MXFMA(A, B, C) __builtin_amdgcn_mfma_scale_f32_32x32x64_f8f6f4( \
    (A), (B), (C), 0, 0, 0, 0x7F7F7F7F, 0, 0x7F7F7F7F)
#define GLDS(g, l) __builtin_amdgcn_global_load_lds( \
    (const __attribute__((address_space(1))) void*)(g), \
    (__attribute__((address_space(3))) void*)(l), 16, 0, 0)

__global__ __launch_bounds__(512, 4) void gemm_lse_mx(const uchar* __restrict__ Apk,
                                                      const uchar* __restrict__ Bpk,
                                                      float2* __restrict__ part) {
  __shared__ uchar lds[3][24576];      // [ring][A 4 frags (8KB) | B 8 frags (16KB)]
  const int tid = threadIdx.x;
  const int wid = tid >> 6, lane = tid & 63;
  const int wr = wid >> 2, wc = wid & 3;        // 2M x 4N wave grid, wave = 64x64 out
  const int l31 = lane & 31, lhi = lane >> 5;
  const int bid = blockIdx.x;
  const int mb = bid & 15;             // 16 M-blocks share one B panel
  const int nb = bid >> 4;             // 0..499

  // staging: A 512 chunks (c=tid), B 1024 chunks (c=tid, tid+512); frag f = c>>7
  const int sfA = tid >> 7, siA = tid & 127;
  const uchar* sgA = Apk + ((size_t)(mb * 4 + sfA) * NT64) * 2048 + siA * 16;
  const int sfB0 = tid >> 7, siB0 = tid & 127;
  const int c1 = tid + 512;
  const int sfB1 = c1 >> 7, siB1 = c1 & 127;
  const uchar* sgB0 = Bpk + ((size_t)(nb * 8 + sfB0) * NT64) * 2048 + siB0 * 16;
  const uchar* sgB1 = Bpk + ((size_t)(nb * 8 + sfB1) * NT64) * 2048 + siB1 * 16;

  f32x16 acc[2][2];
  #pragma unroll
  for (int i = 0; i < 2; ++i)
    #pragma unroll
    for (int j = 0; j < 2; ++j)
      #pragma unroll
      for (int r = 0; r < 16; ++r)
        acc[i][j][r] = 0.f;

  #define STAGE(bufp, kt) do { \
    GLDS(sgA + (size_t)(kt) * 2048, (bufp) + tid * 16); \
    GLDS(sgB0 + (size_t)(kt) * 2048, (bufp) + 8192 + tid * 16); \
    GLDS(sgB1 + (size_t)(kt) * 2048, (bufp) + 8192 + c1 * 16); \
  } while (0)

  // prologue: tiles 0,1 staged; vmcnt(3) -> tile0's 3 loads retired
  STAGE(lds[0], 0);
  STAGE(lds[1], 1);
  asm volatile("s_waitcnt vmcnt(3)" ::: "memory");
  __builtin_amdgcn_s_barrier();

  int cur = 0;
  for (int t = 0; t < NT64; ++t) {
    if (t + 2 < NT64) {
      int stg = cur + 2; if (stg >= 3) stg -= 3;
      STAGE(lds[stg], t + 2);
    }
    const uchar* Ar = lds[cur];
    const uchar* Br = lds[cur] + 8192;
    i32x8 a8[2], b8[2];
    #pragma unroll
    for (int mi = 0; mi < 2; ++mi) {
      const uchar* base = Ar + (wr * 2 + mi) * 2048 + lane * 16;
      i32x4 lo = *reinterpret_cast<const i32x4*>(base);
      i32x4 hi = *reinterpret_cast<const i32x4*>(base + 1024);
      a8[mi] = __builtin_shufflevector(lo, hi, 0, 1, 2, 3, 4, 5, 6, 7);
    }
    #pragma unroll
    for (int ni = 0; ni < 2; ++ni) {
      const uchar* base = Br + (wc * 2 + ni) * 2048 + lane * 16;
      i32x4 lo = *reinterpret_cast<const i32x4*>(base);
      i32x4 hi = *reinterpret_cast<const i32x4*>(base + 1024);
      b8[ni] = __builtin_shufflevector(lo, hi, 0, 1, 2, 3, 4, 5, 6, 7);
    }
    __builtin_amdgcn_s_setprio(1);
    acc[0][0] = MXFMA(a8[0], b8[0], acc[0][0]);
    acc[0][1] = MXFMA(a8[0], b8[1], acc[0][1]);
    acc[1][0] = MXFMA(a8[1], b8[0], acc[1][0]);
    acc[1][1] = MXFMA(a8[1], b8[1], acc[1][1]);
    __builtin_amdgcn_s_setprio(0);
    if (t + 1 < NT64) {
      if (t + 2 < NT64) asm volatile("s_waitcnt vmcnt(3)" ::: "memory");
      else              asm volatile("s_waitcnt vmcnt(0)" ::: "memory");
      __builtin_amdgcn_s_barrier();
    }
    cur = cur + 1; if (cur >= 3) cur = 0;
  }
  #undef STAGE

  // fused partial-LSE epilogue. 32x32 C/D layout (m74/m101, shape-determined
  // for f8f6f4 per m121-128): col = lane&31, row = (reg&3)+8*(reg>>2)+4*(lane>>5).
  // Per (mi,reg): lane holds cols {l31, 32+l31} via ni; reduce over the 32-lane
  // half (shfl_xor d<32 stays within half); lanes 0 and 32 write rows r, r+4.
  const int chunk = nb * 4 + wc;
  #pragma unroll
  for (int mi = 0; mi < 2; ++mi) {
    #pragma unroll
    for (int reg = 0; reg < 16; ++reg) {
      float v0 = acc[mi][0][reg], v1 = acc[mi][1][reg];
      float mloc = fmaxf(v0, v1);
      #pragma unroll
      for (int d = 1; d < 32; d <<= 1) mloc = fmaxf(mloc, __shfl_xor(mloc, d));
      float sloc = __expf(v0 - mloc) + __expf(v1 - mloc);
      #pragma unroll
      for (int d = 1; d < 32; d <<= 1) sloc += __shfl_xor(sloc, d);
      if (l31 == 0) {
        int rlocal = (reg & 3) + 8 * (reg >> 2) + 4 * lhi;
        int grow = mb * 128 + wr * 64 + mi * 32 + rlocal;
        part[(size_t)grow * NCHUNK + chunk] = make_float2(mloc, sloc);
      }
    }
  }
}

// ---------------- per-row merge of partials -> nll[row] ----------------
__device__ __forceinline__ void merge_ms(float& m, float& s, float m2, float s2) {
  if (m2 > m) { s = s * __expf(m - m2) + s2; m = m2; }
  else        { s += s2 * __expf(m2 - m); }
}

__global__ void lse_reduce(const float2* __restrict__ part, const float* __restrict__ tgt,
                           const int* __restrict__ targets, float* __restrict__ nll) {
  int row = blockIdx.x;
  const float2* p = part + (size_t)row * NCHUNK;
  float m = -INFINITY, s = 0.f;
  for (int c = threadIdx.x; c < NCHUNK; c += blockDim.x) {
    float2 v = p[c];
    merge_ms(m, s, v.x, v.y);
  }
  #pragma unroll
  for (int d = 1; d < 64; d <<= 1) {
    float m2 = __shfl_xor(m, d), s2 = __shfl_xor(s, d);
    merge_ms(m, s, m2, s2);
  }
  __shared__ float sm[4], ss[4];
  int wid = threadIdx.x >> 6, lane = threadIdx.x & 63;
  if (lane == 0) { sm[wid] = m; ss[wid] = s; }
  __syncthreads();
  if (threadIdx.x == 0) {
    #pragma unroll
    for (int w2 = 1; w2 < 4; ++w2) merge_ms(m, s, sm[w2], ss[w2]);
    int t = targets[row];
    float out = 0.f;
    if (t != IGNORE_INDEX) out = m + logf(s) - tgt[row];
    nll[row] = out;
  }
}

// ---------------- final scalar: sum(nll)/count ----------------
__global__ void final_kernel(const float* __restrict__ nll, const int* __restrict__ targets,
                             float* __restrict__ out) {
  float sum = 0.f, cnt = 0.f;
  for (int i = threadIdx.x; i < Mrows; i += 64) {
    sum += nll[i];
    cnt += (targets[i] != IGNORE_INDEX) ? 1.f : 0.f;
  }
  #pragma unroll
  for (int d = 1; d < 64; d <<= 1) {
    sum += __shfl_xor(sum, d);
    cnt += __shfl_xor(cnt, d);
  }
  if (threadIdx.x == 0)
    out[0] = (cnt == 0.f) ? sum : sum / fmaxf(cnt, 1.f);
}

extern "C" void kernel_launch(void* const* d_in, const int* in_sizes, int n_in,
                              void* d_out, int out_size, void* d_ws, size_t ws_size,
                              hipStream_t stream) {
  const float* hidden = (const float*)d_in[0];   // [2,1024,1024] f32
  const float* weight = (const float*)d_in[1];   // [128000,1024] f32
  const int* targets  = (const int*)d_in[2];     // [2,1024] i32
  float* out = (float*)d_out;

  char* ws = (char*)d_ws;
  size_t off = 0;
  uchar* w8 = (uchar*)(ws + off); off += (size_t)Vc * Dc;                  // 128 MB
  uchar* h8 = (uchar*)(ws + off); off += (size_t)Mrows * Dc;               // 2 MB
  float2* part = (float2*)(ws + off); off += (size_t)Mrows * NCHUNK * sizeof(float2); // 32 MB
  float* tgt = (float*)(ws + off); off += Mrows * sizeof(float);
  float* nll = (float*)(ws + off); off += Mrows * sizeof(float);
  (void)ws_size; (void)in_sizes; (void)n_in; (void)out_size;

  cast_f32_fp8_pack<<<2048, 256, 0, stream>>>(weight, w8, (size_t)Vc * Dc / 8);
  cast_f32_fp8_pack<<<256, 256, 0, stream>>>(hidden, h8, (size_t)Mrows * Dc / 8);
  tgt_kernel<<<Mrows / 4, 256, 0, stream>>>(hidden, weight, targets, tgt);

  gemm_lse_mx<<<8000, 512, 0, stream>>>(h8, w8, part);  // mb=bid&15, nb=bid>>4

  lse_reduce<<<Mrows, 256, 0, stream>>>(part, tgt, targets, nll);
  final_kernel<<<1, 64, 0, stream>>>(nll, targets, out);
}

// Round 21
// 1839.429 us; speedup vs baseline: 1.5197x; 1.5197x over previous
//
#include <hip/hip_runtime.h>
#include <hip/hip_bf16.h>
#include <hip/hip_fp8.h>
#include <math.h>

#define IGNORE_INDEX (-100)

static constexpr int Dc = 1024, Vc = 128000;
static constexpr int Mrows = 2048;        // B*S
static constexpr int Kdim = 1024;
static constexpr int NT64 = Kdim / 64;    // 16 k-tiles of 64 fp8 elems
static constexpr int NCHUNK = Vc / 64;    // 2000 partial chunks per row

typedef int i32x4 __attribute__((ext_vector_type(4)));
typedef int i32x8 __attribute__((ext_vector_type(8)));
typedef float f32x16 __attribute__((ext_vector_type(16)));

// ---- cast fp32 -> fp8 e4m3, FRAGMENT-MAJOR pack for 32x32x64 MX MFMA -------
// (verified R20: GEMM passed with absmax 0 using this pack)
// Frag tile = 32 rows x 64 k = 2048 B: lane = (row&31) + 32*((k>>5)&1),
// byte pos = ((k>>4)&1)*1024 + lane*16 + (k&15). Any k-bijection is correct as
// long as A and B packs share it (k-permutation-invariant dot; unit scales).
__global__ void cast_f32_fp8_pack(const float* __restrict__ in, uchar* __restrict__ out,
                                  size_t n8) {
  size_t i = (size_t)blockIdx.x * blockDim.x + threadIdx.x;
  size_t stride = (size_t)gridDim.x * blockDim.x;
  for (; i < n8; i += stride) {
    size_t q = i * 8;                      // output byte
    size_t ftile = q >> 11;                // rt*NT64 + kt
    int rem = (int)(q & 2047);
    int chunk = rem >> 10;                 // (k>>4)&1
    int lane = (rem >> 4) & 63;
    int sub0 = rem & 15;                   // 0 or 8
    size_t rt = ftile >> 4;                // / NT64
    int kt = (int)(ftile & 15);
    size_t row = rt * 32 + (lane & 31);
    int k = kt * 64 + (lane >> 5) * 32 + chunk * 16 + sub0;
    const float* p = in + row * Kdim + k;
    float4 v0 = *reinterpret_cast<const float4*>(p);
    float4 v1 = *reinterpret_cast<const float4*>(p + 4);
    union { uchar b[8]; unsigned long long u; } o;
    o.b[0] = __hip_fp8_e4m3(v0.x).__x; o.b[1] = __hip_fp8_e4m3(v0.y).__x;
    o.b[2] = __hip_fp8_e4m3(v0.z).__x; o.b[3] = __hip_fp8_e4m3(v0.w).__x;
    o.b[4] = __hip_fp8_e4m3(v1.x).__x; o.b[5] = __hip_fp8_e4m3(v1.y).__x;
    o.b[6] = __hip_fp8_e4m3(v1.z).__x; o.b[7] = __hip_fp8_e4m3(v1.w).__x;
    reinterpret_cast<unsigned long long*>(out)[i] = o.u;
  }
}

// ---------------- target logits: fp32 dot(hidden[r], weight[t[r]]) — exact ----
__global__ void tgt_kernel(const float* __restrict__ hidden, const float* __restrict__ weight,
                           const int* __restrict__ targets, float* __restrict__ tgt) {
  int row = blockIdx.x * 4 + (threadIdx.x >> 6);
  int lane = threadIdx.x & 63;
  if (row >= Mrows) return;
  int t = targets[row];
  float sum = 0.f;
  if (t != IGNORE_INDEX) {
    const float* h = hidden + (size_t)row * Kdim;
    const float* wv = weight + (size_t)t * Kdim;
    for (int k = lane * 4; k < Kdim; k += 64 * 4) {
      float4 a = *reinterpret_cast<const float4*>(h + k);
      float4 b = *reinterpret_cast<const float4*>(wv + k);
      sum += a.x * b.x + a.y * b.y + a.z * b.z + a.w * b.w;
    }
  }
  #pragma unroll
  for (int d = 1; d < 64; d <<= 1) sum += __shfl_xor(sum, d);
  if (lane == 0) tgt[row] = sum;
}

// -- 128x256 8-wave ring-3 MX-FP8 GEMM + fused partial LSE -------------------
// R20 lesson: __launch_bounds__(512,4) caps the UNIFIED VGPR+AGPR budget at
// ~128/wave; this kernel needs ~140 (acc 64 + operands 32 + addr) -> the
// compiler spilled acc to scratch (WRITE_SIZE 32MB->5.4GB, MfmaUtil 4%).
// FIX: (512,2) -> 256-reg cap, no spill; 1 block/CU. Floors: MFMA 114us
// (4686 TF MX rate), LDS-read 157us -> spill removal should land 250-350us.
#define MXFMA(A, B, C) __builtin_amdgcn_mfma_scale_f32_32x32x64_f8f6f4( \
    (A), (B), (C), 0, 0, 0, 0x7F7F7F7F, 0, 0x7F7F7F7F)
#define GLDS(g, l) __builtin_amdgcn_global_load_lds( \
    (const __attribute__((address_space(1))) void*)(g), \
    (__attribute__((address_space(3))) void*)(l), 16, 0, 0)

__global__ __launch_bounds__(512, 2) void gemm_lse_mx(const uchar* __restrict__ Apk,
                                                      const uchar* __restrict__ Bpk,
                                                      float2* __restrict__ part) {
  __shared__ uchar lds[3][24576];      // [ring][A 4 frags (8KB) | B 8 frags (16KB)]
  const int tid = threadIdx.x;
  const int wid = tid >> 6, lane = tid & 63;
  const int wr = wid >> 2, wc = wid & 3;        // 2M x 4N wave grid, wave = 64x64 out
  const int l31 = lane & 31, lhi = lane >> 5;
  const int bid = blockIdx.x;
  const int mb = bid & 15;             // 16 M-blocks share one B panel
  const int nb = bid >> 4;             // 0..499

  // staging: A 512 chunks (c=tid), B 1024 chunks (c=tid, tid+512); frag f = c>>7
  const int sfA = tid >> 7, siA = tid & 127;
  const uchar* sgA = Apk + ((size_t)(mb * 4 + sfA) * NT64) * 2048 + siA * 16;
  const int sfB0 = tid >> 7, siB0 = tid & 127;
  const int c1 = tid + 512;
  const int sfB1 = c1 >> 7, siB1 = c1 & 127;
  const uchar* sgB0 = Bpk + ((size_t)(nb * 8 + sfB0) * NT64) * 2048 + siB0 * 16;
  const uchar* sgB1 = Bpk + ((size_t)(nb * 8 + sfB1) * NT64) * 2048 + siB1 * 16;

  f32x16 acc[2][2];
  #pragma unroll
  for (int i = 0; i < 2; ++i)
    #pragma unroll
    for (int j = 0; j < 2; ++j)
      #pragma unroll
      for (int r = 0; r < 16; ++r)
        acc[i][j][r] = 0.f;

  #define STAGE(bufp, kt) do { \
    GLDS(sgA + (size_t)(kt) * 2048, (bufp) + tid * 16); \
    GLDS(sgB0 + (size_t)(kt) * 2048, (bufp) + 8192 + tid * 16); \
    GLDS(sgB1 + (size_t)(kt) * 2048, (bufp) + 8192 + c1 * 16); \
  } while (0)

  // prologue: tiles 0,1 staged; vmcnt(3) -> tile0's 3 loads retired
  STAGE(lds[0], 0);
  STAGE(lds[1], 1);
  asm volatile("s_waitcnt vmcnt(3)" ::: "memory");
  __builtin_amdgcn_s_barrier();

  int cur = 0;
  for (int t = 0; t < NT64; ++t) {
    if (t + 2 < NT64) {
      int stg = cur + 2; if (stg >= 3) stg -= 3;
      STAGE(lds[stg], t + 2);
    }
    const uchar* Ar = lds[cur];
    const uchar* Br = lds[cur] + 8192;
    i32x8 a8[2], b8[2];
    #pragma unroll
    for (int mi = 0; mi < 2; ++mi) {
      const uchar* base = Ar + (wr * 2 + mi) * 2048 + lane * 16;
      i32x4 lo = *reinterpret_cast<const i32x4*>(base);
      i32x4 hi = *reinterpret_cast<const i32x4*>(base + 1024);
      a8[mi] = __builtin_shufflevector(lo, hi, 0, 1, 2, 3, 4, 5, 6, 7);
    }
    #pragma unroll
    for (int ni = 0; ni < 2; ++ni) {
      const uchar* base = Br + (wc * 2 + ni) * 2048 + lane * 16;
      i32x4 lo = *reinterpret_cast<const i32x4*>(base);
      i32x4 hi = *reinterpret_cast<const i32x4*>(base + 1024);
      b8[ni] = __builtin_shufflevector(lo, hi, 0, 1, 2, 3, 4, 5, 6, 7);
    }
    __builtin_amdgcn_s_setprio(1);
    acc[0][0] = MXFMA(a8[0], b8[0], acc[0][0]);
    acc[0][1] = MXFMA(a8[0], b8[1], acc[0][1]);
    acc[1][0] = MXFMA(a8[1], b8[0], acc[1][0]);
    acc[1][1] = MXFMA(a8[1], b8[1], acc[1][1]);
    __builtin_amdgcn_s_setprio(0);
    if (t + 1 < NT64) {
      if (t + 2 < NT64) asm volatile("s_waitcnt vmcnt(3)" ::: "memory");
      else              asm volatile("s_waitcnt vmcnt(0)" ::: "memory");
      __builtin_amdgcn_s_barrier();
    }
    cur = cur + 1; if (cur >= 3) cur = 0;
  }
  #undef STAGE

  // fused partial-LSE epilogue. 32x32 C/D layout (m74/m101, shape-determined
  // for f8f6f4 per m121-128): col = lane&31, row = (reg&3)+8*(reg>>2)+4*(lane>>5).
  const int chunk = nb * 4 + wc;
  #pragma unroll
  for (int mi = 0; mi < 2; ++mi) {
    #pragma unroll
    for (int reg = 0; reg < 16; ++reg) {
      float v0 = acc[mi][0][reg], v1 = acc[mi][1][reg];
      float mloc = fmaxf(v0, v1);
      #pragma unroll
      for (int d = 1; d < 32; d <<= 1) mloc = fmaxf(mloc, __shfl_xor(mloc, d));
      float sloc = __expf(v0 - mloc) + __expf(v1 - mloc);
      #pragma unroll
      for (int d = 1; d < 32; d <<= 1) sloc += __shfl_xor(sloc, d);
      if (l31 == 0) {
        int rlocal = (reg & 3) + 8 * (reg >> 2) + 4 * lhi;
        int grow = mb * 128 + wr * 64 + mi * 32 + rlocal;
        part[(size_t)grow * NCHUNK + chunk] = make_float2(mloc, sloc);
      }
    }
  }
}

// ---------------- per-row merge of partials -> nll[row] ----------------
__device__ __forceinline__ void merge_ms(float& m, float& s, float m2, float s2) {
  if (m2 > m) { s = s * __expf(m - m2) + s2; m = m2; }
  else        { s += s2 * __expf(m2 - m); }
}

__global__ void lse_reduce(const float2* __restrict__ part, const float* __restrict__ tgt,
                           const int* __restrict__ targets, float* __restrict__ nll) {
  int row = blockIdx.x;
  const float2* p = part + (size_t)row * NCHUNK;
  float m = -INFINITY, s = 0.f;
  for (int c = threadIdx.x; c < NCHUNK; c += blockDim.x) {
    float2 v = p[c];
    merge_ms(m, s, v.x, v.y);
  }
  #pragma unroll
  for (int d = 1; d < 64; d <<= 1) {
    float m2 = __shfl_xor(m, d), s2 = __shfl_xor(s, d);
    merge_ms(m, s, m2, s2);
  }
  __shared__ float sm[4], ss[4];
  int wid = threadIdx.x >> 6, lane = threadIdx.x & 63;
  if (lane == 0) { sm[wid] = m; ss[wid] = s; }
  __syncthreads();
  if (threadIdx.x == 0) {
    #pragma unroll
    for (int w2 = 1; w2 < 4; ++w2) merge_ms(m, s, sm[w2], ss[w2]);
    int t = targets[row];
    float out = 0.f;
    if (t != IGNORE_INDEX) out = m + logf(s) - tgt[row];
    nll[row] = out;
  }
}

// ---------------- final scalar: sum(nll)/count ----------------
__global__ void final_kernel(const float* __restrict__ nll, const int* __restrict__ targets,
                             float* __restrict__ out) {
  float sum = 0.f, cnt = 0.f;
  for (int i = threadIdx.x; i < Mrows; i += 64) {
    sum += nll[i];
    cnt += (targets[i] != IGNORE_INDEX) ? 1.f : 0.f;
  }
  #pragma unroll
  for (int d = 1; d < 64; d <<= 1) {
    sum += __shfl_xor(sum, d);
    cnt += __shfl_xor(cnt, d);
  }
  if (threadIdx.x == 0)
    out[0] = (cnt == 0.f) ? sum : sum / fmaxf(cnt, 1.f);
}

extern "C" void kernel_launch(void* const* d_in, const int* in_sizes, int n_in,
                              void* d_out, int out_size, void* d_ws, size_t ws_size,
                              hipStream_t stream) {
  const float* hidden = (const float*)d_in[0];   // [2,1024,1024] f32
  const float* weight = (const float*)d_in[1];   // [128000,1024] f32
  const int* targets  = (const int*)d_in[2];     // [2,1024] i32
  float* out = (float*)d_out;

  char* ws = (char*)d_ws;
  size_t off = 0;
  uchar* w8 = (uchar*)(ws + off); off += (size_t)Vc * Dc;                  // 128 MB
  uchar* h8 = (uchar*)(ws + off); off += (size_t)Mrows * Dc;               // 2 MB
  float2* part = (float2*)(ws + off); off += (size_t)Mrows * NCHUNK * sizeof(float2); // 32 MB
  float* tgt = (float*)(ws + off); off += Mrows * sizeof(float);
  float* nll = (float*)(ws + off); off += Mrows * sizeof(float);
  (void)ws_size; (void)in_sizes; (void)n_in; (void)out_size;

  cast_f32_fp8_pack<<<2048, 256, 0, stream>>>(weight, w8, (size_t)Vc * Dc / 8);
  cast_f32_fp8_pack<<<256, 256, 0, stream>>>(hidden, h8, (size_t)Mrows * Dc / 8);
  tgt_kernel<<<Mrows / 4, 256, 0, stream>>>(hidden, weight, targets, tgt);

  gemm_lse_mx<<<8000, 512, 0, stream>>>(h8, w8, part);  // mb=bid&15, nb=bid>>4

  lse_reduce<<<Mrows, 256, 0, stream>>>(part, tgt, targets, nll);
  final_kernel<<<1, 64, 0, stream>>>(nll, targets, out);
}

// Round 22
// 1552.920 us; speedup vs baseline: 1.8001x; 1.1845x over previous
//
#include <hip/hip_runtime.h>
#include <hip/hip_bf16.h>
#include <hip/hip_fp8.h>
#include <math.h>

#define IGNORE_INDEX (-100)

static constexpr int Dc = 1024, Vc = 128000;
static constexpr int Mrows = 2048;        // B*S
static constexpr int Kdim = 1024;
static constexpr int NT64 = Kdim / 64;    // 16 k-tiles of 64 fp8 elems
static constexpr int NCHUNK = Vc / 32;    // 4000 partial chunks (32 cols) per row

typedef int i32x4 __attribute__((ext_vector_type(4)));
typedef int i32x8 __attribute__((ext_vector_type(8)));
typedef float f32x16 __attribute__((ext_vector_type(16)));

// ---- cast fp32 -> fp8 e4m3, FRAGMENT-MAJOR pack for 32x32x64 MX MFMA -------
// (numerics verified R20/R21: absmax 0.0)
// Frag tile = 32 rows x 64 k = 2048 B: lane = (row&31) + 32*((k>>5)&1),
// byte pos = ((k>>4)&1)*1024 + lane*16 + (k&15). Any k-bijection is correct as
// long as A and B packs share it (k-permutation-invariant dot; unit scales).
__global__ void cast_f32_fp8_pack(const float* __restrict__ in, uchar* __restrict__ out,
                                  size_t n8) {
  size_t i = (size_t)blockIdx.x * blockDim.x + threadIdx.x;
  size_t stride = (size_t)gridDim.x * blockDim.x;
  for (; i < n8; i += stride) {
    size_t q = i * 8;                      // output byte
    size_t ftile = q >> 11;                // rt*NT64 + kt
    int rem = (int)(q & 2047);
    int chunk = rem >> 10;                 // (k>>4)&1
    int lane = (rem >> 4) & 63;
    int sub0 = rem & 15;                   // 0 or 8
    size_t rt = ftile >> 4;                // / NT64
    int kt = (int)(ftile & 15);
    size_t row = rt * 32 + (lane & 31);
    int k = kt * 64 + (lane >> 5) * 32 + chunk * 16 + sub0;
    const float* p = in + row * Kdim + k;
    float4 v0 = *reinterpret_cast<const float4*>(p);
    float4 v1 = *reinterpret_cast<const float4*>(p + 4);
    union { uchar b[8]; unsigned long long u; } o;
    o.b[0] = __hip_fp8_e4m3(v0.x).__x; o.b[1] = __hip_fp8_e4m3(v0.y).__x;
    o.b[2] = __hip_fp8_e4m3(v0.z).__x; o.b[3] = __hip_fp8_e4m3(v0.w).__x;
    o.b[4] = __hip_fp8_e4m3(v1.x).__x; o.b[5] = __hip_fp8_e4m3(v1.y).__x;
    o.b[6] = __hip_fp8_e4m3(v1.z).__x; o.b[7] = __hip_fp8_e4m3(v1.w).__x;
    reinterpret_cast<unsigned long long*>(out)[i] = o.u;
  }
}

// ---------------- target logits: fp32 dot(hidden[r], weight[t[r]]) — exact ----
__global__ void tgt_kernel(const float* __restrict__ hidden, const float* __restrict__ weight,
                           const int* __restrict__ targets, float* __restrict__ tgt) {
  int row = blockIdx.x * 4 + (threadIdx.x >> 6);
  int lane = threadIdx.x & 63;
  if (row >= Mrows) return;
  int t = targets[row];
  float sum = 0.f;
  if (t != IGNORE_INDEX) {
    const float* h = hidden + (size_t)row * Kdim;
    const float* wv = weight + (size_t)t * Kdim;
    for (int k = lane * 4; k < Kdim; k += 64 * 4) {
      float4 a = *reinterpret_cast<const float4*>(h + k);
      float4 b = *reinterpret_cast<const float4*>(wv + k);
      sum += a.x * b.x + a.y * b.y + a.z * b.z + a.w * b.w;
    }
  }
  #pragma unroll
  for (int d = 1; d < 64; d <<= 1) sum += __shfl_xor(sum, d);
  if (lane == 0) tgt[row] = sum;
}

// -- 128x128 8-wave ring-3 MX-FP8 GEMM + fused partial LSE -------------------
// R20/R21 lesson: 64x64 wave (acc 64 + ops 32 + scaled-MFMA legalization)
// exceeds the register budget -> acc spilled to scratch (WRITE_SIZE GBs,
// MfmaUtil 6.5%, kernel scratch-BW-bound). THIS ROUND: wave = 64x32 (2x1
// frags of 32x32): acc = 32 regs, operands 24 -> demand ~100, no spill even
// at a 128 cap. Block 128x128; LDS tile 16KB, ring-3 48KB; 2 GLDS/thread/tile
// -> counted vmcnt(2) (R13-proven wave-uniform pattern). MX MFMA rate = 2x
// non-scaled fp8 (4686 TF m59): MFMA floor 114us.
#define MXFMA(A, B, C) __builtin_amdgcn_mfma_scale_f32_32x32x64_f8f6f4( \
    (A), (B), (C), 0, 0, 0, 0x7F7F7F7F, 0, 0x7F7F7F7F)
#define GLDS(g, l) __builtin_amdgcn_global_load_lds( \
    (const __attribute__((address_space(1))) void*)(g), \
    (__attribute__((address_space(3))) void*)(l), 16, 0, 0)

__global__ __launch_bounds__(512, 2) void gemm_lse_mx(const uchar* __restrict__ Apk,
                                                      const uchar* __restrict__ Bpk,
                                                      float2* __restrict__ part) {
  __shared__ uchar lds[3][16384];      // [ring][A 4 frags (8KB) | B 4 frags (8KB)]
  const int tid = threadIdx.x;
  const int wid = tid >> 6, lane = tid & 63;
  const int wr = wid >> 2, wc = wid & 3;        // 2M x 4N wave grid, wave = 64x32 out
  const int l31 = lane & 31, lhi = lane >> 5;
  const int bid = blockIdx.x;
  const int mb = bid & 15;             // Mrows/128 = 16 M-blocks
  const int nb = bid >> 4;             // 0..999 (V/128)

  // staging: A 512 chunks (c=tid: frag c>>7, idx c&127); B same
  const uchar* sgA = Apk + ((size_t)(mb * 4 + (tid >> 7)) * NT64) * 2048 + (tid & 127) * 16;
  const uchar* sgB = Bpk + ((size_t)(nb * 4 + (tid >> 7)) * NT64) * 2048 + (tid & 127) * 16;

  f32x16 acc[2];
  #pragma unroll
  for (int i = 0; i < 2; ++i)
    #pragma unroll
    for (int r = 0; r < 16; ++r)
      acc[i][r] = 0.f;

  #define STAGE(bufp, kt) do { \
    GLDS(sgA + (size_t)(kt) * 2048, (bufp) + tid * 16); \
    GLDS(sgB + (size_t)(kt) * 2048, (bufp) + 8192 + tid * 16); \
  } while (0)

  // prologue: tiles 0,1 staged; vmcnt(2) -> tile0's 2 loads retired
  STAGE(lds[0], 0);
  STAGE(lds[1], 1);
  asm volatile("s_waitcnt vmcnt(2)" ::: "memory");
  __builtin_amdgcn_s_barrier();

  int cur = 0;
  for (int t = 0; t < NT64; ++t) {
    if (t + 2 < NT64) {
      int stg = cur + 2; if (stg >= 3) stg -= 3;
      STAGE(lds[stg], t + 2);
    }
    const uchar* Ar = lds[cur];
    const uchar* Br = lds[cur] + 8192;
    i32x8 a8[2], b8;
    #pragma unroll
    for (int mi = 0; mi < 2; ++mi) {
      const uchar* base = Ar + (wr * 2 + mi) * 2048 + lane * 16;
      i32x4 lo = *reinterpret_cast<const i32x4*>(base);
      i32x4 hi = *reinterpret_cast<const i32x4*>(base + 1024);
      a8[mi] = __builtin_shufflevector(lo, hi, 0, 1, 2, 3, 4, 5, 6, 7);
    }
    {
      const uchar* base = Br + wc * 2048 + lane * 16;
      i32x4 lo = *reinterpret_cast<const i32x4*>(base);
      i32x4 hi = *reinterpret_cast<const i32x4*>(base + 1024);
      b8 = __builtin_shufflevector(lo, hi, 0, 1, 2, 3, 4, 5, 6, 7);
    }
    __builtin_amdgcn_s_setprio(1);
    acc[0] = MXFMA(a8[0], b8, acc[0]);
    acc[1] = MXFMA(a8[1], b8, acc[1]);
    __builtin_amdgcn_s_setprio(0);
    if (t + 1 < NT64) {
      if (t + 2 < NT64) asm volatile("s_waitcnt vmcnt(2)" ::: "memory");
      else              asm volatile("s_waitcnt vmcnt(0)" ::: "memory");
      __builtin_amdgcn_s_barrier();
    }
    cur = cur + 1; if (cur >= 3) cur = 0;
  }
  #undef STAGE

  // fused partial-LSE epilogue. 32x32 C/D layout (m74/m101, shape-determined
  // for f8f6f4 per m121-128): col = lane&31, row = (reg&3)+8*(reg>>2)+4*(lane>>5).
  // Wave covers 32 cols -> one 32-col chunk; reduce over the 32-lane half
  // (shfl_xor d<32 stays within half); lanes 0/32 write rows r, r+4.
  const int chunk = nb * 4 + wc;
  #pragma unroll
  for (int mi = 0; mi < 2; ++mi) {
    #pragma unroll
    for (int reg = 0; reg < 16; ++reg) {
      float v = acc[mi][reg];
      float mloc = v;
      #pragma unroll
      for (int d = 1; d < 32; d <<= 1) mloc = fmaxf(mloc, __shfl_xor(mloc, d));
      float sloc = __expf(v - mloc);
      #pragma unroll
      for (int d = 1; d < 32; d <<= 1) sloc += __shfl_xor(sloc, d);
      if (l31 == 0) {
        int rlocal = (reg & 3) + 8 * (reg >> 2) + 4 * lhi;
        int grow = mb * 128 + wr * 64 + mi * 32 + rlocal;
        part[(size_t)grow * NCHUNK + chunk] = make_float2(mloc, sloc);
      }
    }
  }
}

// ---------------- per-row merge of partials -> nll[row] ----------------
__device__ __forceinline__ void merge_ms(float& m, float& s, float m2, float s2) {
  if (m2 > m) { s = s * __expf(m - m2) + s2; m = m2; }
  else        { s += s2 * __expf(m2 - m); }
}

__global__ void lse_reduce(const float2* __restrict__ part, const float* __restrict__ tgt,
                           const int* __restrict__ targets, float* __restrict__ nll) {
  int row = blockIdx.x;
  const float2* p = part + (size_t)row * NCHUNK;
  float m = -INFINITY, s = 0.f;
  for (int c = threadIdx.x; c < NCHUNK; c += blockDim.x) {
    float2 v = p[c];
    merge_ms(m, s, v.x, v.y);
  }
  #pragma unroll
  for (int d = 1; d < 64; d <<= 1) {
    float m2 = __shfl_xor(m, d), s2 = __shfl_xor(s, d);
    merge_ms(m, s, m2, s2);
  }
  __shared__ float sm[4], ss[4];
  int wid = threadIdx.x >> 6, lane = threadIdx.x & 63;
  if (lane == 0) { sm[wid] = m; ss[wid] = s; }
  __syncthreads();
  if (threadIdx.x == 0) {
    #pragma unroll
    for (int w2 = 1; w2 < 4; ++w2) merge_ms(m, s, sm[w2], ss[w2]);
    int t = targets[row];
    float out = 0.f;
    if (t != IGNORE_INDEX) out = m + logf(s) - tgt[row];
    nll[row] = out;
  }
}

// ---------------- final scalar: sum(nll)/count ----------------
__global__ void final_kernel(const float* __restrict__ nll, const int* __restrict__ targets,
                             float* __restrict__ out) {
  float sum = 0.f, cnt = 0.f;
  for (int i = threadIdx.x; i < Mrows; i += 64) {
    sum += nll[i];
    cnt += (targets[i] != IGNORE_INDEX) ? 1.f : 0.f;
  }
  #pragma unroll
  for (int d = 1; d < 64; d <<= 1) {
    sum += __shfl_xor(sum, d);
    cnt += __shfl_xor(cnt, d);
  }
  if (threadIdx.x == 0)
    out[0] = (cnt == 0.f) ? sum : sum / fmaxf(cnt, 1.f);
}

extern "C" void kernel_launch(void* const* d_in, const int* in_sizes, int n_in,
                              void* d_out, int out_size, void* d_ws, size_t ws_size,
                              hipStream_t stream) {
  const float* hidden = (const float*)d_in[0];   // [2,1024,1024] f32
  const float* weight = (const float*)d_in[1];   // [128000,1024] f32
  const int* targets  = (const int*)d_in[2];     // [2,1024] i32
  float* out = (float*)d_out;

  char* ws = (char*)d_ws;
  size_t off = 0;
  uchar* w8 = (uchar*)(ws + off); off += (size_t)Vc * Dc;                  // 128 MB
  uchar* h8 = (uchar*)(ws + off); off += (size_t)Mrows * Dc;               // 2 MB
  float2* part = (float2*)(ws + off); off += (size_t)Mrows * NCHUNK * sizeof(float2); // 65.5 MB
  float* tgt = (float*)(ws + off); off += Mrows * sizeof(float);
  float* nll = (float*)(ws + off); off += Mrows * sizeof(float);
  (void)ws_size; (void)in_sizes; (void)n_in; (void)out_size;

  cast_f32_fp8_pack<<<2048, 256, 0, stream>>>(weight, w8, (size_t)Vc * Dc / 8);
  cast_f32_fp8_pack<<<256, 256, 0, stream>>>(hidden, h8, (size_t)Mrows * Dc / 8);
  tgt_kernel<<<Mrows / 4, 256, 0, stream>>>(hidden, weight, targets, tgt);

  gemm_lse_mx<<<16000, 512, 0, stream>>>(h8, w8, part);  // mb=bid&15, nb=bid>>4

  lse_reduce<<<Mrows, 256, 0, stream>>>(part, tgt, targets, nll);
  final_kernel<<<1, 64, 0, stream>>>(nll, targets, out);
}